// Round 2
// baseline (1059.146 us; speedup 1.0000x reference)
//
#include <hip/hip_runtime.h>
#include <hip/hip_bf16.h>

#define D 128

__device__ __forceinline__ float bf2f(__hip_bfloat16 x) { return __bfloat162float(x); }
__device__ __forceinline__ float lo_bf(unsigned u) { return __uint_as_float(u << 16); }
__device__ __forceinline__ float hi_bf(unsigned u) { return __uint_as_float(u & 0xFFFF0000u); }

// ---------------- Stage 0: detect float dtype (1 = bf16 pairs, 0 = float32) ----------------
// bf16-pair words carry the low element's exponent in bits 14:7 -> clustered in [120,130]
// for unit-normal data (~99%). f32 words have uniform mantissa bits there (~4%).
__global__ void detect_kernel(const unsigned* __restrict__ words, int nwords, int* __restrict__ flag) {
    __shared__ int cnt[256];
    int tid = threadIdx.x;
    int c = 0;
    for (int i = tid; i < nwords; i += 256) {
        unsigned e = (words[i] >> 7) & 0xFF;
        if (e >= 120 && e <= 130) c++;
    }
    cnt[tid] = c;
    __syncthreads();
    for (int s = 128; s > 0; s >>= 1) {
        if (tid < s) cnt[tid] += cnt[tid + s];
        __syncthreads();
    }
    if (tid == 0) *flag = (2 * cnt[0] > nwords) ? 1 : 0;
}

// ---------------- Stage 1: in-degrees ----------------
__global__ void deg_kernel(const int* __restrict__ dst, int* __restrict__ degs, int E) {
    int i = blockIdx.x * blockDim.x + threadIdx.x;
    if (i < E) atomicAdd(&degs[dst[i]], 1);
}

// ---------------- Stage 2: h = nfeat @ W^T + b (fp32), norm = rsqrt(deg+1) ----------------
// W transposed into LDS: wt[k*128 + d] = W[d][k]. Reads wt[k*128+lane] are
// consecutive across lanes -> 2-way bank aliasing only (free). One node per wave;
// x broadcast via __shfl (readlane). 64 KB LDS exactly.
__global__ __launch_bounds__(256) void h_kernel(
    const void* __restrict__ nfeat, const void* __restrict__ W, const void* __restrict__ b,
    const int* __restrict__ degs, const int* __restrict__ flag_p,
    float* __restrict__ norm, float* __restrict__ h, int N)
{
    __shared__ float wt[128 * 128];   // 65536 B
    const int tid = threadIdx.x;
    const int isbf = *flag_p;

    for (int i = blockIdx.x * 256 + tid; i < N; i += gridDim.x * 256)
        norm[i] = rsqrtf((float)degs[i] + 1.0f);

    if (isbf) {
        const unsigned* Wu = (const unsigned*)W;        // pair (d,2k2),(d,2k2+1)
        for (int i = tid; i < 128 * 64; i += 256) {
            int d = i >> 6, k2 = i & 63;
            unsigned u = Wu[d * 64 + k2];
            wt[(2 * k2) * 128 + d]     = lo_bf(u);
            wt[(2 * k2 + 1) * 128 + d] = hi_bf(u);
        }
    } else {
        const float* Wf = (const float*)W;
        for (int i = tid; i < 128 * 128; i += 256) {
            int d = i >> 7, k = i & 127;
            wt[k * 128 + d] = Wf[d * 128 + k];
        }
    }
    __syncthreads();

    const int lane = tid & 63;
    const int wave = tid >> 6;
    float b0, b1;
    if (isbf) { const __hip_bfloat16* bb = (const __hip_bfloat16*)b; b0 = bf2f(bb[lane]); b1 = bf2f(bb[lane + 64]); }
    else      { const float* bf = (const float*)b; b0 = bf[lane]; b1 = bf[lane + 64]; }

    const int stride = gridDim.x * 4;
    for (int n = blockIdx.x * 4 + wave; n < N; n += stride) {
        float2 x2;
        if (isbf) {
            unsigned u = ((const unsigned*)nfeat)[(size_t)n * 64 + lane];
            x2.x = lo_bf(u); x2.y = hi_bf(u);
        } else {
            x2 = ((const float2*)nfeat)[(size_t)n * 64 + lane];
        }
        float acc0 = b0, acc1 = b1;
        #pragma unroll
        for (int k2 = 0; k2 < 64; ++k2) {
            float xa = __shfl(x2.x, k2);
            float xb = __shfl(x2.y, k2);
            acc0 = fmaf(xa, wt[(2 * k2) * 128 + lane],          acc0);
            acc1 = fmaf(xa, wt[(2 * k2) * 128 + lane + 64],     acc1);
            acc0 = fmaf(xb, wt[(2 * k2 + 1) * 128 + lane],      acc0);
            acc1 = fmaf(xb, wt[(2 * k2 + 1) * 128 + lane + 64], acc1);
        }
        h[(size_t)n * D + lane]      = acc0;
        h[(size_t)n * D + lane + 64] = acc1;
    }
}

// ---------------- Stage 3: edge messages, scatter-add into fp32 agg ----------------
__global__ __launch_bounds__(256) void edge_kernel(
    const int* __restrict__ src, const int* __restrict__ dstv, const int* __restrict__ efeat,
    const float* __restrict__ norm, const float* __restrict__ h,
    const void* __restrict__ edge_embed, const int* __restrict__ flag_p,
    float* __restrict__ agg, int E)
{
    const int isbf = *flag_p;
    const int lane   = threadIdx.x & 63;
    const int wave   = (blockIdx.x * blockDim.x + threadIdx.x) >> 6;
    const int nwaves = (gridDim.x * blockDim.x) >> 6;
    const int c = lane * 2;

    for (int e = wave; e < E; e += nwaves) {
        int s = src[e], dt = dstv[e], t = efeat[e];
        float en = norm[s] * norm[dt];
        const float2 hv = *(const float2*)(h + (size_t)s * D + c);
        float e0, e1;
        if (isbf) {
            unsigned u = ((const unsigned*)edge_embed)[t * 64 + lane];
            e0 = lo_bf(u); e1 = hi_bf(u);
        } else {
            float2 ev = ((const float2*)edge_embed)[t * 64 + lane];
            e0 = ev.x; e1 = ev.y;
        }
        float m0 = fmaxf(hv.x + e0, 0.0f) * en;
        float m1 = fmaxf(hv.y + e1, 0.0f) * en;
        float* arow = agg + (size_t)dt * D + c;
        unsafeAtomicAdd(arow,     m0);
        unsafeAtomicAdd(arow + 1, m1);
    }
}

// ---------------- Stage 4: out = agg + relu(h + res_w) / deg ----------------
__global__ __launch_bounds__(256) void final_kernel(
    const float* __restrict__ agg, const float* __restrict__ h,
    const int* __restrict__ degs, const void* __restrict__ res_w,
    const int* __restrict__ flag_p, void* __restrict__ out, int N)
{
    const int isbf = *flag_p;
    int i = blockIdx.x * blockDim.x + threadIdx.x;   // pair index
    int total = N * (D / 2);
    if (i >= total) return;
    size_t idx = (size_t)i * 2;
    int n = (int)(idx >> 7);
    int d = (int)(idx & 127);
    float invdeg = 1.0f / ((float)degs[n] + 1.0f);
    float r0, r1;
    if (isbf) { const __hip_bfloat16* rw = (const __hip_bfloat16*)res_w; r0 = bf2f(rw[d]); r1 = bf2f(rw[d + 1]); }
    else      { const float* rw = (const float*)res_w; r0 = rw[d]; r1 = rw[d + 1]; }
    float o0 = agg[idx]     + fmaxf(h[idx]     + r0, 0.0f) * invdeg;
    float o1 = agg[idx + 1] + fmaxf(h[idx + 1] + r1, 0.0f) * invdeg;
    if (isbf) {
        __hip_bfloat16* o = (__hip_bfloat16*)out;
        o[idx]     = __float2bfloat16(o0);
        o[idx + 1] = __float2bfloat16(o1);
    } else {
        float* o = (float*)out;
        o[idx]     = o0;
        o[idx + 1] = o1;
    }
}

extern "C" void kernel_launch(void* const* d_in, const int* in_sizes, int n_in,
                              void* d_out, int out_size, void* d_ws, size_t ws_size,
                              hipStream_t stream) {
    const void* nfeat = d_in[0];
    const int* efeat  = (const int*)d_in[1];
    const int* src    = (const int*)d_in[2];
    const int* dst    = (const int*)d_in[3];
    const void* W     = d_in[4];
    const void* b     = d_in[5];
    const void* ee    = d_in[6];
    const void* res_w = d_in[7];

    const int N = in_sizes[0] / D;
    const int E = in_sizes[2];

    // workspace (fp32 words): agg[N*D] | degs[N] (int) | norm[N] | flag + pad(64) | h[N*D]
    float* ws   = (float*)d_ws;
    float* agg  = ws;
    int*   degs = (int*)(ws + (size_t)N * D);
    float* norm = (float*)(degs + N);
    int*   flag = (int*)(norm + N);
    float* h    = (float*)(flag + 64);

    hipMemsetAsync(agg, 0, ((size_t)N * D + N) * sizeof(float), stream);

    detect_kernel<<<1, 256, 0, stream>>>((const unsigned*)nfeat, 1024, flag);
    deg_kernel<<<(E + 255) / 256, 256, 0, stream>>>(dst, degs, E);
    h_kernel<<<1024, 256, 0, stream>>>(nfeat, W, b, degs, flag, norm, h, N);
    edge_kernel<<<2048, 256, 0, stream>>>(src, dst, efeat, norm, h, ee, flag, agg, E);
    final_kernel<<<(N * (D / 2) + 255) / 256, 256, 0, stream>>>(agg, h, degs, res_w, flag, d_out, N);
}

// Round 4
// 422.120 us; speedup vs baseline: 2.5091x; 2.5091x over previous
//
#include <hip/hip_runtime.h>
#include <hip/hip_bf16.h>

#define D 128

typedef short short8 __attribute__((ext_vector_type(8)));
typedef float f32x4  __attribute__((ext_vector_type(4)));

__device__ __forceinline__ float lo_bf(unsigned u) { return __uint_as_float(u << 16); }
__device__ __forceinline__ float hi_bf(unsigned u) { return __uint_as_float(u & 0xFFFF0000u); }

// ---------------- Stage 1: in-degrees ----------------
__global__ void deg_kernel(const int* __restrict__ dst, int* __restrict__ degs, int E) {
    int i = blockIdx.x * blockDim.x + threadIdx.x;
    if (i < E) atomicAdd(&degs[dst[i]], 1);
}

// ---------------- Stage 2: single-block scan -> offsets, cursors, norm ----------------
__global__ __launch_bounds__(1024) void scan_kernel(
    const int* __restrict__ degs, int* __restrict__ off, int* __restrict__ cursor,
    float* __restrict__ norm, int N, int E)
{
    __shared__ int sums[1024];
    const int tid = threadIdx.x;
    const int chunk = (N + 1023) >> 10;
    const int b0 = tid * chunk;
    const int e0 = min(b0 + chunk, N);
    int s = 0;
    for (int i = b0; i < e0; ++i) s += degs[i];
    sums[tid] = s;
    __syncthreads();
    for (int o = 1; o < 1024; o <<= 1) {           // inclusive Hillis-Steele
        int v = (tid >= o) ? sums[tid - o] : 0;
        __syncthreads();
        sums[tid] += v;
        __syncthreads();
    }
    int run = sums[tid] - s;                        // exclusive prefix
    for (int i = b0; i < e0; ++i) {
        int d = degs[i];
        off[i] = run;
        cursor[i] = run;
        norm[i] = rsqrtf((float)d + 1.0f);
        run += d;
    }
    if (tid == 1023) off[N] = E;
}

// ---------------- Stage 3: fill CSR (packed src | et<<20) ----------------
__global__ void fill_kernel(const int* __restrict__ src, const int* __restrict__ dst,
                            const int* __restrict__ efeat, int* __restrict__ cursor,
                            unsigned* __restrict__ csr, int E) {
    int i = blockIdx.x * blockDim.x + threadIdx.x;
    if (i >= E) return;
    int d = dst[i];
    int pos = atomicAdd(&cursor[d], 1);
    csr[pos] = (unsigned)src[i] | ((unsigned)efeat[i] << 20);
}

// ---------------- Stage 4a: split W (f32) into truncated-bf16 hi/lo planes ----------------
__global__ void wsplit_kernel(const float* __restrict__ W, short* __restrict__ whi,
                              short* __restrict__ wlo) {
    int i = blockIdx.x * blockDim.x + threadIdx.x;
    if (i >= D * D) return;
    float w = W[i];
    unsigned u = __float_as_uint(w);
    float hi = __uint_as_float(u & 0xFFFF0000u);
    float lo = w - hi;
    whi[i] = (short)(u >> 16);
    wlo[i] = (short)(__float_as_uint(lo) >> 16);
}

// ---------------- Stage 4b: h = x @ W^T + b via split-bf16 MFMA (f32-accurate) ----------------
// 16x16x32 bf16 MFMA. A-frag: lane holds A[m=lane&15][k=quad*8+j]; B^T input: B-frag
// loads W[n=lane&15][k=quad*8+j] (row-major W). C/D: n=lane&15, m=quad*4+reg.
__global__ __launch_bounds__(256) void h_mfma_kernel(
    const float* __restrict__ x, const short* __restrict__ whi, const short* __restrict__ wlo,
    const float* __restrict__ b, __hip_bfloat16* __restrict__ hbf, int N)
{
    const int lane = threadIdx.x & 63;
    const int wave = threadIdx.x >> 6;
    const int m0 = (blockIdx.x * 4 + wave) * 16;
    if (m0 >= N) return;
    const int row  = lane & 15;
    const int quad = lane >> 4;
    int mrow = m0 + row; if (mrow >= N) mrow = N - 1;   // safe dup for ragged tail

    f32x4 acc[8];
    #pragma unroll
    for (int t = 0; t < 8; ++t) acc[t] = (f32x4){0.f, 0.f, 0.f, 0.f};

    #pragma unroll
    for (int kk = 0; kk < 4; ++kk) {
        const int ko = kk * 32 + quad * 8;
        const float* xp = x + (size_t)mrow * D + ko;
        short8 ahi, alo;
        #pragma unroll
        for (int j = 0; j < 8; ++j) {
            float xv = xp[j];
            unsigned u = __float_as_uint(xv);
            float hi = __uint_as_float(u & 0xFFFF0000u);
            float lo = xv - hi;
            ahi[j] = (short)(u >> 16);
            alo[j] = (short)(__float_as_uint(lo) >> 16);
        }
        #pragma unroll
        for (int t = 0; t < 8; ++t) {
            const short8 bhi = *(const short8*)(whi + (size_t)(t * 16 + row) * D + ko);
            const short8 blo = *(const short8*)(wlo + (size_t)(t * 16 + row) * D + ko);
            acc[t] = __builtin_amdgcn_mfma_f32_16x16x32_bf16(ahi, bhi, acc[t], 0, 0, 0);
            acc[t] = __builtin_amdgcn_mfma_f32_16x16x32_bf16(ahi, blo, acc[t], 0, 0, 0);
            acc[t] = __builtin_amdgcn_mfma_f32_16x16x32_bf16(alo, bhi, acc[t], 0, 0, 0);
        }
    }

    #pragma unroll
    for (int t = 0; t < 8; ++t) {
        const int col = t * 16 + row;
        const float bias = b[col];
        #pragma unroll
        for (int r = 0; r < 4; ++r) {
            const int m = m0 + quad * 4 + r;
            if (m < N) hbf[(size_t)m * D + col] = __float2bfloat16(acc[t][r] + bias);
        }
    }
}

// ---------------- Stage 5: gather-aggregate per dst node + fused residual, f32 out ----------------
__global__ __launch_bounds__(256) void agg_kernel(
    const int* __restrict__ off, const unsigned* __restrict__ csr,
    const float* __restrict__ norm, const unsigned* __restrict__ hbf,
    const float* __restrict__ ee, const float* __restrict__ res_w,
    float2* __restrict__ out, int N)
{
    __shared__ float ee0[16 * 64], ee1[16 * 64];   // even/odd channel planes
    const int tid = threadIdx.x;
    for (int i = tid; i < 16 * 64; i += 256) {
        int et = i >> 6, ln = i & 63;
        ee0[i] = ee[(et << 7) + 2 * ln];
        ee1[i] = ee[(et << 7) + 2 * ln + 1];
    }
    __syncthreads();

    const int n = blockIdx.x * 4 + (tid >> 6);
    if (n >= N) return;
    const int lane = tid & 63;

    const int beg = off[n], end = off[n + 1];
    const int deg = end - beg;
    const float nd = norm[n];

    float acc0 = 0.f, acc1 = 0.f;
    for (int base = beg; base < end; base += 64) {
        int idx = base + lane;
        unsigned se = 0; float en = 0.f;
        if (idx < end) {
            se = csr[idx];
            en = norm[se & 0xFFFFF] * nd;
        }
        int cnt = min(64, end - base);
        #pragma unroll 4
        for (int j = 0; j < cnt; ++j) {
            unsigned sej = (unsigned)__shfl((int)se, j);
            float enj = __shfl(en, j);
            int sj  = sej & 0xFFFFF;
            int etj = sej >> 20;
            unsigned hw = hbf[((size_t)sj << 6) + lane];
            float m0 = fmaxf(lo_bf(hw) + ee0[(etj << 6) + lane], 0.f);
            float m1 = fmaxf(hi_bf(hw) + ee1[(etj << 6) + lane], 0.f);
            acc0 = fmaf(m0, enj, acc0);
            acc1 = fmaf(m1, enj, acc1);
        }
    }

    // residual: relu(h + res_w) / (deg+1)
    unsigned hn = hbf[((size_t)n << 6) + lane];
    float2 rw = ((const float2*)res_w)[lane];
    float invd = 1.0f / (float)(deg + 1);
    float r0 = fmaxf(lo_bf(hn) + rw.x, 0.f) * invd;
    float r1 = fmaxf(hi_bf(hn) + rw.y, 0.f) * invd;
    out[((size_t)n << 6) + lane] = make_float2(acc0 + r0, acc1 + r1);
}

extern "C" void kernel_launch(void* const* d_in, const int* in_sizes, int n_in,
                              void* d_out, int out_size, void* d_ws, size_t ws_size,
                              hipStream_t stream) {
    const float* nfeat = (const float*)d_in[0];
    const int* efeat   = (const int*)d_in[1];
    const int* src     = (const int*)d_in[2];
    const int* dst     = (const int*)d_in[3];
    const float* W     = (const float*)d_in[4];
    const float* b     = (const float*)d_in[5];
    const float* ee    = (const float*)d_in[6];
    const float* res_w = (const float*)d_in[7];

    const int N = in_sizes[0] / D;
    const int E = in_sizes[2];

    // workspace: degs[N] | off[N+1] | cursor[N] | norm[N] | csr[E] | whi | wlo | hbf[N*D]
    char* p = (char*)d_ws;
    int* degs      = (int*)p;      p += (size_t)N * 4;
    int* off       = (int*)p;      p += (size_t)(N + 1) * 4;
    int* cursor    = (int*)p;      p += (size_t)N * 4;
    float* norm    = (float*)p;    p += (size_t)N * 4;
    p = (char*)(((uintptr_t)p + 15) & ~(uintptr_t)15);
    unsigned* csr  = (unsigned*)p; p += (size_t)E * 4;
    p = (char*)(((uintptr_t)p + 15) & ~(uintptr_t)15);
    short* whi     = (short*)p;    p += (size_t)D * D * 2;
    short* wlo     = (short*)p;    p += (size_t)D * D * 2;
    p = (char*)(((uintptr_t)p + 15) & ~(uintptr_t)15);
    __hip_bfloat16* hbf = (__hip_bfloat16*)p;

    hipMemsetAsync(degs, 0, (size_t)N * 4, stream);

    deg_kernel<<<(E + 255) / 256, 256, 0, stream>>>(dst, degs, E);
    wsplit_kernel<<<(D * D + 255) / 256, 256, 0, stream>>>(W, whi, wlo);
    scan_kernel<<<1, 1024, 0, stream>>>(degs, off, cursor, norm, N, E);
    fill_kernel<<<(E + 255) / 256, 256, 0, stream>>>(src, dst, efeat, cursor, csr, E);

    const int mtiles = (N + 15) / 16;
    h_mfma_kernel<<<(mtiles + 3) / 4, 256, 0, stream>>>(nfeat, whi, wlo, b, hbf, N);
    agg_kernel<<<(N + 3) / 4, 256, 0, stream>>>(off, csr, norm, (const unsigned*)hbf,
                                                ee, res_w, (float2*)d_out, N);
}

// Round 5
// 285.132 us; speedup vs baseline: 3.7146x; 1.4804x over previous
//
#include <hip/hip_runtime.h>
#include <hip/hip_bf16.h>

#define D 128

typedef short short8 __attribute__((ext_vector_type(8)));
typedef float f32x4  __attribute__((ext_vector_type(4)));

__device__ __forceinline__ float lo_bf(unsigned u) { return __uint_as_float(u << 16); }
__device__ __forceinline__ float hi_bf(unsigned u) { return __uint_as_float(u & 0xFFFF0000u); }

// ---------------- Stage 1: in-degrees ----------------
__global__ void deg_kernel(const int* __restrict__ dst, int* __restrict__ degs, int E) {
    int i = blockIdx.x * blockDim.x + threadIdx.x;
    if (i < E) atomicAdd(&degs[dst[i]], 1);
}

// ---------------- Stage 2a: per-block degree sums + norm ----------------
__global__ __launch_bounds__(256) void scan_blocks(
    const int* __restrict__ degs, int* __restrict__ blocksum,
    float* __restrict__ norm, int N)
{
    const int tid = threadIdx.x;
    const int i = blockIdx.x * 256 + tid;
    int d = (i < N) ? degs[i] : 0;
    if (i < N) norm[i] = rsqrtf((float)d + 1.0f);

    int v = d;
    #pragma unroll
    for (int o = 32; o > 0; o >>= 1) v += __shfl_down(v, o, 64);
    __shared__ int ws[4];
    if ((tid & 63) == 0) ws[tid >> 6] = v;
    __syncthreads();
    if (tid == 0) blocksum[blockIdx.x] = ws[0] + ws[1] + ws[2] + ws[3];
}

// ---------------- Stage 2b: scan block sums (nb <= 256) ----------------
__global__ __launch_bounds__(256) void scan_top(
    const int* __restrict__ blocksum, int* __restrict__ blockoff, int nb)
{
    __shared__ int s[256];
    const int tid = threadIdx.x;
    s[tid] = (tid < nb) ? blocksum[tid] : 0;
    __syncthreads();
    for (int o = 1; o < 256; o <<= 1) {
        int v = (tid >= o) ? s[tid - o] : 0;
        __syncthreads();
        s[tid] += v;
        __syncthreads();
    }
    if (tid < nb) blockoff[tid] = s[tid] - blocksum[tid];   // exclusive
}

// ---------------- Stage 2c: final offsets ----------------
__global__ __launch_bounds__(256) void scan_final(
    const int* __restrict__ degs, const int* __restrict__ blockoff,
    int* __restrict__ off, int* __restrict__ cursor, int N, int E)
{
    const int tid = threadIdx.x;
    const int i = blockIdx.x * 256 + tid;
    const int lane = tid & 63, w = tid >> 6;
    int d = (i < N) ? degs[i] : 0;

    int v = d;                                   // wave inclusive scan
    #pragma unroll
    for (int o = 1; o < 64; o <<= 1) {
        int t = __shfl_up(v, o, 64);
        if (lane >= o) v += t;
    }
    __shared__ int ws[4];
    if (lane == 63) ws[w] = v;
    __syncthreads();
    int woff = 0;
    #pragma unroll
    for (int k = 0; k < 4; ++k) if (k < w) woff += ws[k];

    int excl = blockoff[blockIdx.x] + woff + v - d;
    if (i < N) { off[i] = excl; cursor[i] = excl; }
    if (blockIdx.x == 0 && tid == 0) off[N] = E;
}

// ---------------- Stage 3: fill CSR (packed src | et<<20) ----------------
__global__ void fill_kernel(const int* __restrict__ src, const int* __restrict__ dst,
                            const int* __restrict__ efeat, int* __restrict__ cursor,
                            unsigned* __restrict__ csr, int E) {
    int i = blockIdx.x * blockDim.x + threadIdx.x;
    if (i >= E) return;
    int d = dst[i];
    int pos = atomicAdd(&cursor[d], 1);
    csr[pos] = (unsigned)src[i] | ((unsigned)efeat[i] << 20);
}

// ---------------- Stage 4a: split W (f32) into truncated-bf16 hi/lo planes ----------------
__global__ void wsplit_kernel(const float* __restrict__ W, short* __restrict__ whi,
                              short* __restrict__ wlo) {
    int i = blockIdx.x * blockDim.x + threadIdx.x;
    if (i >= D * D) return;
    float w = W[i];
    unsigned u = __float_as_uint(w);
    float hi = __uint_as_float(u & 0xFFFF0000u);
    float lo = w - hi;
    whi[i] = (short)(u >> 16);
    wlo[i] = (short)(__float_as_uint(lo) >> 16);
}

// ---------------- Stage 4b: h = x @ W^T + b via split-bf16 MFMA (f32-accurate) ----------------
__global__ __launch_bounds__(256) void h_mfma_kernel(
    const float* __restrict__ x, const short* __restrict__ whi, const short* __restrict__ wlo,
    const float* __restrict__ b, __hip_bfloat16* __restrict__ hbf, int N)
{
    const int lane = threadIdx.x & 63;
    const int wave = threadIdx.x >> 6;
    const int m0 = (blockIdx.x * 4 + wave) * 16;
    if (m0 >= N) return;
    const int row  = lane & 15;
    const int quad = lane >> 4;
    int mrow = m0 + row; if (mrow >= N) mrow = N - 1;   // safe dup for ragged tail

    f32x4 acc[8];
    #pragma unroll
    for (int t = 0; t < 8; ++t) acc[t] = (f32x4){0.f, 0.f, 0.f, 0.f};

    #pragma unroll
    for (int kk = 0; kk < 4; ++kk) {
        const int ko = kk * 32 + quad * 8;
        const float* xp = x + (size_t)mrow * D + ko;
        short8 ahi, alo;
        #pragma unroll
        for (int j = 0; j < 8; ++j) {
            float xv = xp[j];
            unsigned u = __float_as_uint(xv);
            float hi = __uint_as_float(u & 0xFFFF0000u);
            float lo = xv - hi;
            ahi[j] = (short)(u >> 16);
            alo[j] = (short)(__float_as_uint(lo) >> 16);
        }
        #pragma unroll
        for (int t = 0; t < 8; ++t) {
            const short8 bhi = *(const short8*)(whi + (size_t)(t * 16 + row) * D + ko);
            const short8 blo = *(const short8*)(wlo + (size_t)(t * 16 + row) * D + ko);
            acc[t] = __builtin_amdgcn_mfma_f32_16x16x32_bf16(ahi, bhi, acc[t], 0, 0, 0);
            acc[t] = __builtin_amdgcn_mfma_f32_16x16x32_bf16(ahi, blo, acc[t], 0, 0, 0);
            acc[t] = __builtin_amdgcn_mfma_f32_16x16x32_bf16(alo, bhi, acc[t], 0, 0, 0);
        }
    }

    #pragma unroll
    for (int t = 0; t < 8; ++t) {
        const int col = t * 16 + row;
        const float bias = b[col];
        #pragma unroll
        for (int r = 0; r < 4; ++r) {
            const int m = m0 + quad * 4 + r;
            if (m < N) hbf[(size_t)m * D + col] = __float2bfloat16(acc[t][r] + bias);
        }
    }
}

// ---------------- Stage 5: gather-aggregate per dst node + fused residual, f32 out ----------------
__global__ __launch_bounds__(256) void agg_kernel(
    const int* __restrict__ off, const unsigned* __restrict__ csr,
    const float* __restrict__ norm, const unsigned* __restrict__ hbf,
    const float* __restrict__ ee, const float* __restrict__ res_w,
    float2* __restrict__ out, int N)
{
    __shared__ float ee0[16 * 64], ee1[16 * 64];   // even/odd channel planes
    const int tid = threadIdx.x;
    for (int i = tid; i < 16 * 64; i += 256) {
        int et = i >> 6, ln = i & 63;
        ee0[i] = ee[(et << 7) + 2 * ln];
        ee1[i] = ee[(et << 7) + 2 * ln + 1];
    }
    __syncthreads();

    const int n = blockIdx.x * 4 + (tid >> 6);
    if (n >= N) return;
    const int lane = tid & 63;

    const int beg = off[n], end = off[n + 1];
    const int deg = end - beg;
    const float nd = norm[n];

    float acc0 = 0.f, acc1 = 0.f;
    for (int base = beg; base < end; base += 64) {
        int idx = base + lane;
        unsigned se = 0; float en = 0.f;
        if (idx < end) {
            se = csr[idx];
            en = norm[se & 0xFFFFF] * nd;
        }
        int cnt = min(64, end - base);
        #pragma unroll 4
        for (int j = 0; j < cnt; ++j) {
            unsigned sej = (unsigned)__shfl((int)se, j);
            float enj = __shfl(en, j);
            int sj  = sej & 0xFFFFF;
            int etj = sej >> 20;
            unsigned hw = hbf[((size_t)sj << 6) + lane];
            float m0 = fmaxf(lo_bf(hw) + ee0[(etj << 6) + lane], 0.f);
            float m1 = fmaxf(hi_bf(hw) + ee1[(etj << 6) + lane], 0.f);
            acc0 = fmaf(m0, enj, acc0);
            acc1 = fmaf(m1, enj, acc1);
        }
    }

    // residual: relu(h + res_w) / (deg+1)
    unsigned hn = hbf[((size_t)n << 6) + lane];
    float2 rw = ((const float2*)res_w)[lane];
    float invd = 1.0f / (float)(deg + 1);
    float r0 = fmaxf(lo_bf(hn) + rw.x, 0.f) * invd;
    float r1 = fmaxf(hi_bf(hn) + rw.y, 0.f) * invd;
    out[((size_t)n << 6) + lane] = make_float2(acc0 + r0, acc1 + r1);
}

extern "C" void kernel_launch(void* const* d_in, const int* in_sizes, int n_in,
                              void* d_out, int out_size, void* d_ws, size_t ws_size,
                              hipStream_t stream) {
    const float* nfeat = (const float*)d_in[0];
    const int* efeat   = (const int*)d_in[1];
    const int* src     = (const int*)d_in[2];
    const int* dst     = (const int*)d_in[3];
    const float* W     = (const float*)d_in[4];
    const float* b     = (const float*)d_in[5];
    const float* ee    = (const float*)d_in[6];
    const float* res_w = (const float*)d_in[7];

    const int N = in_sizes[0] / D;
    const int E = in_sizes[2];
    const int nb = (N + 255) / 256;   // 196 <= 256

    // workspace: degs | off | cursor | norm | blocksum | blockoff | csr | whi | wlo | hbf
    char* p = (char*)d_ws;
    int* degs      = (int*)p;      p += (size_t)N * 4;
    int* off       = (int*)p;      p += (size_t)(N + 1) * 4;
    int* cursor    = (int*)p;      p += (size_t)N * 4;
    float* norm    = (float*)p;    p += (size_t)N * 4;
    int* blocksum  = (int*)p;      p += 256 * 4;
    int* blockoff  = (int*)p;      p += 256 * 4;
    p = (char*)(((uintptr_t)p + 15) & ~(uintptr_t)15);
    unsigned* csr  = (unsigned*)p; p += (size_t)E * 4;
    p = (char*)(((uintptr_t)p + 15) & ~(uintptr_t)15);
    short* whi     = (short*)p;    p += (size_t)D * D * 2;
    short* wlo     = (short*)p;    p += (size_t)D * D * 2;
    p = (char*)(((uintptr_t)p + 15) & ~(uintptr_t)15);
    __hip_bfloat16* hbf = (__hip_bfloat16*)p;

    hipMemsetAsync(degs, 0, (size_t)N * 4, stream);

    deg_kernel<<<(E + 255) / 256, 256, 0, stream>>>(dst, degs, E);
    wsplit_kernel<<<(D * D + 255) / 256, 256, 0, stream>>>(W, whi, wlo);
    scan_blocks<<<nb, 256, 0, stream>>>(degs, blocksum, norm, N);
    scan_top<<<1, 256, 0, stream>>>(blocksum, blockoff, nb);
    scan_final<<<nb, 256, 0, stream>>>(degs, blockoff, off, cursor, N, E);
    fill_kernel<<<(E + 255) / 256, 256, 0, stream>>>(src, dst, efeat, cursor, csr, E);

    const int mtiles = (N + 15) / 16;
    h_mfma_kernel<<<(mtiles + 3) / 4, 256, 0, stream>>>(nfeat, whi, wlo, b, hbf, N);
    agg_kernel<<<(N + 3) / 4, 256, 0, stream>>>(off, csr, norm, (const unsigned*)hbf,
                                                ee, res_w, (float2*)d_out, N);
}